// Round 2
// baseline (163.488 us; speedup 1.0000x reference)
//
#include <hip/hip_runtime.h>

#define NN 100     // N nodes
#define D  128     // d_model
#define BB 128     // batch
#define PP 4950    // pairs

__device__ inline void fma4(float4& a, float s, const float4& w) {
    a.x = fmaf(s, w.x, a.x);
    a.y = fmaf(s, w.y, a.y);
    a.z = fmaf(s, w.z, a.z);
    a.w = fmaf(s, w.w, a.w);
}

// ws layout (floats): u[128], v[100*128]
// grid 101 x 128 threads. blocks 0..99 -> v rows; block 100 -> u.
__global__ __launch_bounds__(128)
void pe_v_kernel(const float* __restrict__ w_dist,
                 const float* __restrict__ b_dist,
                 const float* __restrict__ w1,
                 const float* __restrict__ b1,
                 float* __restrict__ ws) {
    __shared__ float pe_l[D];
    const int n = blockIdx.x;
    const int t = threadIdx.x;   // 0..127

    if (n == NN) {
        // u[e] = sum_d w_dist[d] * w1[d,e]
        float acc = 0.f;
        #pragma unroll 4
        for (int dd = 0; dd < D; ++dd) acc = fmaf(w_dist[dd], w1[dd * D + t], acc);
        ws[t] = acc;
        return;
    }

    // pe_row[n, t]
    const int c = t & 3;
    const int q = t >> 2;
    const float kf = (float)(4 * q);
    const float LOG1E4_OVER_D = 9.210340371976184f / 128.0f; // ln(10000)/d
    float val;
    if (c == 0) {
        float inv = expf(-kf * LOG1E4_OVER_D);
        val = (float)NN * sinf((float)n * inv);
    } else if (c == 1) {
        float inv = expf(-kf * LOG1E4_OVER_D);
        val = (float)NN * cosf((float)n * inv);
    } else if (c == 2) {
        float inv = expf(-(kf + 2.0f) * LOG1E4_OVER_D);
        float s = 0.f;
        for (int j = 0; j < NN; ++j) s += sinf((float)j * inv);
        val = s;
    } else {
        float inv = expf(-(kf + 3.0f) * LOG1E4_OVER_D);
        float s = 0.f;
        for (int j = 0; j < NN; ++j) s += cosf(fabsf((float)(n - j)) * inv);
        val = s;
    }
    pe_l[t] = val;
    __syncthreads();

    // v[n,e] = (sum_d (99*b_dist[d] + pe[d]) * w1[d,e]) / N + b1[e]
    float acc = 0.f;
    #pragma unroll 4
    for (int dd = 0; dd < D; ++dd) {
        float x = fmaf(99.0f, b_dist[dd], pe_l[dd]);
        acc = fmaf(x, w1[dd * D + t], acc);
    }
    ws[D + n * D + t] = acc * (1.0f / (float)NN) + b1[t];
}

// grid 128 (one block per batch) x 256 threads
__global__ __launch_bounds__(256)
void main_kernel(const float* __restrict__ cad,     // [B,P]
                 const float* __restrict__ w2,      // [D,D]
                 const float* __restrict__ b2,      // [D]
                 const float* __restrict__ wo1,     // [D,64]
                 const float* __restrict__ bo1,     // [64]
                 const float* __restrict__ wo2,     // [64,2]
                 const float* __restrict__ bo2,     // [2]
                 const float* __restrict__ ws,      // u[128], v[100*128]
                 float* __restrict__ out) {         // [B,2]
    const int b   = blockIdx.x;
    const int tid = threadIdx.x;

    __shared__ float w2_l[D * D];       // 64 KB, [d][e]
    __shared__ float h1_l[32][D];       // 16 KB
    __shared__ float S_l[NN];
    __shared__ float u_l[D];
    __shared__ float red_l[8 * D];      // 4 KB slot-reduce
    __shared__ float pooled_l[D];
    __shared__ float z_l[64];

    const float* u_g = ws;
    const float* v_g = ws + D;

    // ---- S'[n] = (sum of cad over edges incident to n) / N ----
    if (tid < NN) {
        const int n = tid;
        const float* cb = cad + b * PP;
        float s = 0.f;
        const int base = n * (NN - 1) - (n * (n - 1)) / 2;
        for (int j = n + 1; j < NN; ++j) s += cb[base + (j - n - 1)];
        for (int i = 0; i < n; ++i)
            s += cb[i * (NN - 1) - (i * (i - 1)) / 2 + (n - i - 1)];
        S_l[n] = s * (1.0f / (float)NN);
    }
    if (tid < D) u_l[tid] = u_g[tid];

    // ---- stage w2 into LDS ----
    for (int i = tid; i < D * D / 4; i += 256)
        ((float4*)w2_l)[i] = ((const float4*)w2)[i];
    __syncthreads();

    // thread layout: eq = e-quad (32), slot = row-group (8)
    const int eq   = tid & 31;
    const int slot = tid >> 5;
    const int e0   = eq * 4;
    const float4 b2v = *(const float4*)(b2 + e0);

    float4 pool = {0.f, 0.f, 0.f, 0.f};

    for (int rb = 0; rb < NN; rb += 32) {
        // compute h1 rows rb..rb+31 (rows >= NN padded with 0)
        #pragma unroll
        for (int k = 0; k < 16; ++k) {
            const int idx = k * 256 + tid;
            const int lr = idx >> 7, dd = idx & 127;
            const int g = rb + lr;
            float h = 0.f;
            if (g < NN) h = fmaxf(fmaf(S_l[g], u_l[dd], v_g[g * D + dd]), 0.f);
            h1_l[lr][dd] = h;
        }
        __syncthreads();

        const int lr0 = slot * 4;
        const int g0  = rb + lr0;
        if (g0 < NN) {
            float4 acc0 = {0,0,0,0}, acc1 = {0,0,0,0};
            float4 acc2 = {0,0,0,0}, acc3 = {0,0,0,0};
            #pragma unroll 2
            for (int dd = 0; dd < D; dd += 4) {
                const float4 w0 = *(const float4*)&w2_l[(dd + 0) * D + e0];
                const float4 w1v = *(const float4*)&w2_l[(dd + 1) * D + e0];
                const float4 w2v = *(const float4*)&w2_l[(dd + 2) * D + e0];
                const float4 w3v = *(const float4*)&w2_l[(dd + 3) * D + e0];
                float4 h;
                h = *(const float4*)&h1_l[lr0 + 0][dd];
                fma4(acc0, h.x, w0); fma4(acc0, h.y, w1v); fma4(acc0, h.z, w2v); fma4(acc0, h.w, w3v);
                h = *(const float4*)&h1_l[lr0 + 1][dd];
                fma4(acc1, h.x, w0); fma4(acc1, h.y, w1v); fma4(acc1, h.z, w2v); fma4(acc1, h.w, w3v);
                h = *(const float4*)&h1_l[lr0 + 2][dd];
                fma4(acc2, h.x, w0); fma4(acc2, h.y, w1v); fma4(acc2, h.z, w2v); fma4(acc2, h.w, w3v);
                h = *(const float4*)&h1_l[lr0 + 3][dd];
                fma4(acc3, h.x, w0); fma4(acc3, h.y, w1v); fma4(acc3, h.z, w2v); fma4(acc3, h.w, w3v);
            }
            // h2 = relu(acc + b2); pool += h2   (guard each row)
            if (g0 + 0 < NN) {
                pool.x += fmaxf(acc0.x + b2v.x, 0.f); pool.y += fmaxf(acc0.y + b2v.y, 0.f);
                pool.z += fmaxf(acc0.z + b2v.z, 0.f); pool.w += fmaxf(acc0.w + b2v.w, 0.f);
            }
            if (g0 + 1 < NN) {
                pool.x += fmaxf(acc1.x + b2v.x, 0.f); pool.y += fmaxf(acc1.y + b2v.y, 0.f);
                pool.z += fmaxf(acc1.z + b2v.z, 0.f); pool.w += fmaxf(acc1.w + b2v.w, 0.f);
            }
            if (g0 + 2 < NN) {
                pool.x += fmaxf(acc2.x + b2v.x, 0.f); pool.y += fmaxf(acc2.y + b2v.y, 0.f);
                pool.z += fmaxf(acc2.z + b2v.z, 0.f); pool.w += fmaxf(acc2.w + b2v.w, 0.f);
            }
            if (g0 + 3 < NN) {
                pool.x += fmaxf(acc3.x + b2v.x, 0.f); pool.y += fmaxf(acc3.y + b2v.y, 0.f);
                pool.z += fmaxf(acc3.z + b2v.z, 0.f); pool.w += fmaxf(acc3.w + b2v.w, 0.f);
            }
        }
        __syncthreads();
    }

    // reduce pool across the 8 slots
    red_l[slot * D + e0 + 0] = pool.x;
    red_l[slot * D + e0 + 1] = pool.y;
    red_l[slot * D + e0 + 2] = pool.z;
    red_l[slot * D + e0 + 3] = pool.w;
    __syncthreads();

    if (tid < D) {
        float s = 0.f;
        #pragma unroll
        for (int sl = 0; sl < 8; ++sl) s += red_l[sl * D + tid];
        pooled_l[tid] = s * (1.0f / (float)NN);   // mean over sequence
    }
    __syncthreads();

    // head: z = relu(pooled @ wo1 + bo1)
    if (tid < 64) {
        float acc = bo1[tid];
        #pragma unroll 4
        for (int e = 0; e < D; ++e) acc = fmaf(pooled_l[e], wo1[e * 64 + tid], acc);
        z_l[tid] = fmaxf(acc, 0.f);
    }
    __syncthreads();

    // out = z @ wo2 + bo2
    if (tid < 2) {
        float acc = bo2[tid];
        #pragma unroll 4
        for (int k = 0; k < 64; ++k) acc = fmaf(z_l[k], wo2[k * 2 + tid], acc);
        out[b * 2 + tid] = acc;
    }
}

extern "C" void kernel_launch(void* const* d_in, const int* in_sizes, int n_in,
                              void* d_out, int out_size, void* d_ws, size_t ws_size,
                              hipStream_t stream) {
    const float* cad    = (const float*)d_in[0];
    const float* w_dist = (const float*)d_in[1];
    const float* b_dist = (const float*)d_in[2];
    const float* w1     = (const float*)d_in[3];
    const float* b1     = (const float*)d_in[4];
    const float* w2     = (const float*)d_in[5];
    const float* b2     = (const float*)d_in[6];
    const float* wo1    = (const float*)d_in[7];
    const float* bo1    = (const float*)d_in[8];
    const float* wo2    = (const float*)d_in[9];
    const float* bo2    = (const float*)d_in[10];
    float* ws  = (float*)d_ws;
    float* out = (float*)d_out;

    pe_v_kernel<<<dim3(NN + 1), dim3(128), 0, stream>>>(w_dist, b_dist, w1, b1, ws);
    main_kernel<<<dim3(BB), dim3(256), 0, stream>>>(cad, w2, b2, wo1, bo1, wo2, bo2, ws, out);
}

// Round 4
// 128.506 us; speedup vs baseline: 1.2722x; 1.2722x over previous
//
#include <hip/hip_runtime.h>

#define NN 100     // N nodes
#define D  128     // d_model
#define BB 128     // batch
#define PP 4950    // pairs

// ws float offsets
#define U_OFF    0
#define V_OFF    (D)                    // 128
#define S_OFF    (V_OFF + NN * D)       // 12928
#define POOL_OFF (S_OFF + BB * NN)      // 25728
// total floats: 25728 + 128*128 = 42112 (~165 KB)

__device__ inline void fma4(float4& a, float s, const float4& w) {
    a.x = fmaf(s, w.x, a.x);
    a.y = fmaf(s, w.y, a.y);
    a.z = fmaf(s, w.z, a.z);
    a.w = fmaf(s, w.w, a.w);
}

// ---------------------------------------------------------------------------
// prep: grid 230 x 256
//   blocks   0..99 : v rows (pe + GEMM1 fold)
//   block      100 : u
//   block      101 : zero pooled accumulator
//   blocks 102..229: S[b,n] scatter-sum (b = blk-102)
// ---------------------------------------------------------------------------
__global__ __launch_bounds__(256)
void prep_kernel(const float* __restrict__ cad,
                 const float* __restrict__ w_dist,
                 const float* __restrict__ b_dist,
                 const float* __restrict__ w1,
                 const float* __restrict__ b1,
                 float* __restrict__ ws) {
    const int blk = blockIdx.x;
    const int t   = threadIdx.x;

    if (blk < NN) {
        // ---- pe_row[n,:] then v[n,:] ----
        __shared__ float pe_l[D];
        const int n = blk;
        if (t < D) {
            const int c = t & 3;
            const int q = t >> 2;
            const float kf = (float)(4 * q);
            const float LOG1E4_OVER_D = 9.210340371976184f / 128.0f;
            float val;
            if (c == 0) {
                float inv = expf(-kf * LOG1E4_OVER_D);
                val = (float)NN * sinf((float)n * inv);
            } else if (c == 1) {
                float inv = expf(-kf * LOG1E4_OVER_D);
                val = (float)NN * cosf((float)n * inv);
            } else if (c == 2) {
                float inv = expf(-(kf + 2.0f) * LOG1E4_OVER_D);
                float s = 0.f;
                for (int j = 0; j < NN; ++j) s += sinf((float)j * inv);
                val = s;
            } else {
                float inv = expf(-(kf + 3.0f) * LOG1E4_OVER_D);
                float s = 0.f;
                for (int j = 0; j < NN; ++j) s += cosf(fabsf((float)(n - j)) * inv);
                val = s;
            }
            pe_l[t] = val;
        }
        __syncthreads();
        if (t < D) {
            float acc = 0.f;
            #pragma unroll 4
            for (int dd = 0; dd < D; ++dd) {
                float x = fmaf(99.0f, b_dist[dd], pe_l[dd]);
                acc = fmaf(x, w1[dd * D + t], acc);
            }
            ws[V_OFF + n * D + t] = acc * (1.0f / (float)NN) + b1[t];
        }
    } else if (blk == NN) {
        // ---- u[e] = w_dist @ w1 ----
        if (t < D) {
            float acc = 0.f;
            #pragma unroll 4
            for (int dd = 0; dd < D; ++dd) acc = fmaf(w_dist[dd], w1[dd * D + t], acc);
            ws[U_OFF + t] = acc;
        }
    } else if (blk == NN + 1) {
        // ---- zero pooled[B][D] ----
        float4 z = {0.f, 0.f, 0.f, 0.f};
        for (int i = t; i < BB * D / 4; i += 256)
            ((float4*)(ws + POOL_OFF))[i] = z;
    } else {
        // ---- S'[b,n] = (sum of cad over incident edges)/N ----
        const int b = blk - (NN + 2);
        __shared__ float S_l[NN];
        if (t < NN) S_l[t] = 0.f;
        __syncthreads();
        const float* cb = cad + b * PP;
        for (int p = t; p < PP; p += 256) {
            float val = cb[p];
            // invert p -> (i,j), i<j, triu row-major
            int i = (int)((199.0f - sqrtf((float)(39601 - 8 * p))) * 0.5f);
            // correction (at most one step)
            while (i * (199 - i) / 2 > p) --i;
            while ((i + 1) * (198 - i) / 2 <= p) ++i;
            int j = p - i * (199 - i) / 2 + i + 1;
            atomicAdd(&S_l[i], val);
            atomicAdd(&S_l[j], val);
        }
        __syncthreads();
        if (t < NN) ws[S_OFF + b * NN + t] = S_l[t] * (1.0f / (float)NN);
    }
}

// ---------------------------------------------------------------------------
// gemm2: grid (4 chunks, 128 b) x 256.  Each block: 32 rows x 128 e.
//   h1 staged in LDS (on-the-fly from S,u,v), w2 staged in LDS.
//   partial pool -> global atomicAdd into ws.pooled[b][e].
// LDS: 64K (w2) + 16K (h1, reused for reduce) = 80 KB -> 2 blocks/CU.
// ---------------------------------------------------------------------------
__global__ __launch_bounds__(256)
void gemm2_kernel(const float* __restrict__ w2,      // [D,D]
                  const float* __restrict__ b2,      // [D]
                  const float* __restrict__ ws) {
    const int chunk = blockIdx.x;        // 0..3
    const int b     = blockIdx.y;        // 0..127
    const int tid   = threadIdx.x;
    const int base  = chunk * 32;

    __shared__ float w2_l[D * D];        // 64 KB [d][e]
    __shared__ float h1_l[32 * D];       // 16 KB, reused as red[8][128]

    const float* u_g = ws + U_OFF;
    const float* v_g = ws + V_OFF;
    const float* S_g = ws + S_OFF + b * NN;
    float*       pool_g = (float*)(ws + POOL_OFF) + b * D;

    // stage w2
    for (int i = tid; i < D * D / 4; i += 256)
        ((float4*)w2_l)[i] = ((const float4*)w2)[i];

    // stage h1 rows base..base+31 : thread t -> dd0=(t&31)*4, rows (t>>5)+8k
    {
        const int dd0 = (tid & 31) * 4;
        const int r0  = tid >> 5;
        const float4 uv = *(const float4*)(u_g + dd0);
        #pragma unroll
        for (int k = 0; k < 4; ++k) {
            const int lr = r0 + k * 8;
            const int g  = base + lr;
            float4 h = {0.f, 0.f, 0.f, 0.f};
            if (g < NN) {
                const float s = S_g[g];
                const float4 vv = *(const float4*)(v_g + g * D + dd0);
                h.x = fmaxf(fmaf(s, uv.x, vv.x), 0.f);
                h.y = fmaxf(fmaf(s, uv.y, vv.y), 0.f);
                h.z = fmaxf(fmaf(s, uv.z, vv.z), 0.f);
                h.w = fmaxf(fmaf(s, uv.w, vv.w), 0.f);
            }
            *(float4*)(h1_l + lr * D + dd0) = h;
        }
    }
    __syncthreads();

    // GEMM: thread (slot=tid>>5, eq=tid&31): rows slot*4.., cols eq*4..
    const int eq   = tid & 31;
    const int slot = tid >> 5;
    const int e0   = eq * 4;
    const int lr0  = slot * 4;
    const int g0   = base + lr0;

    float4 pool = {0.f, 0.f, 0.f, 0.f};
    if (g0 < NN) {
        const float4 b2v = *(const float4*)(b2 + e0);
        float4 acc0 = {0,0,0,0}, acc1 = {0,0,0,0};
        float4 acc2 = {0,0,0,0}, acc3 = {0,0,0,0};
        #pragma unroll 2
        for (int dd = 0; dd < D; dd += 4) {
            const float4 w0  = *(const float4*)&w2_l[(dd + 0) * D + e0];
            const float4 w1v = *(const float4*)&w2_l[(dd + 1) * D + e0];
            const float4 w2v = *(const float4*)&w2_l[(dd + 2) * D + e0];
            const float4 w3v = *(const float4*)&w2_l[(dd + 3) * D + e0];
            float4 h;
            h = *(const float4*)&h1_l[(lr0 + 0) * D + dd];
            fma4(acc0, h.x, w0); fma4(acc0, h.y, w1v); fma4(acc0, h.z, w2v); fma4(acc0, h.w, w3v);
            h = *(const float4*)&h1_l[(lr0 + 1) * D + dd];
            fma4(acc1, h.x, w0); fma4(acc1, h.y, w1v); fma4(acc1, h.z, w2v); fma4(acc1, h.w, w3v);
            h = *(const float4*)&h1_l[(lr0 + 2) * D + dd];
            fma4(acc2, h.x, w0); fma4(acc2, h.y, w1v); fma4(acc2, h.z, w2v); fma4(acc2, h.w, w3v);
            h = *(const float4*)&h1_l[(lr0 + 3) * D + dd];
            fma4(acc3, h.x, w0); fma4(acc3, h.y, w1v); fma4(acc3, h.z, w2v); fma4(acc3, h.w, w3v);
        }
        if (g0 + 0 < NN) {
            pool.x += fmaxf(acc0.x + b2v.x, 0.f); pool.y += fmaxf(acc0.y + b2v.y, 0.f);
            pool.z += fmaxf(acc0.z + b2v.z, 0.f); pool.w += fmaxf(acc0.w + b2v.w, 0.f);
        }
        if (g0 + 1 < NN) {
            pool.x += fmaxf(acc1.x + b2v.x, 0.f); pool.y += fmaxf(acc1.y + b2v.y, 0.f);
            pool.z += fmaxf(acc1.z + b2v.z, 0.f); pool.w += fmaxf(acc1.w + b2v.w, 0.f);
        }
        if (g0 + 2 < NN) {
            pool.x += fmaxf(acc2.x + b2v.x, 0.f); pool.y += fmaxf(acc2.y + b2v.y, 0.f);
            pool.z += fmaxf(acc2.z + b2v.z, 0.f); pool.w += fmaxf(acc2.w + b2v.w, 0.f);
        }
        if (g0 + 3 < NN) {
            pool.x += fmaxf(acc3.x + b2v.x, 0.f); pool.y += fmaxf(acc3.y + b2v.y, 0.f);
            pool.z += fmaxf(acc3.z + b2v.z, 0.f); pool.w += fmaxf(acc3.w + b2v.w, 0.f);
        }
    }
    __syncthreads();   // done reading h1_l -> safe to reuse as reduce buffer

    // reduce pool across 8 slots (reuse h1_l as red[8][D])
    *(float4*)(h1_l + slot * D + e0) = pool;
    __syncthreads();
    if (tid < D) {
        float s = 0.f;
        #pragma unroll
        for (int sl = 0; sl < 8; ++sl) s += h1_l[sl * D + tid];
        atomicAdd(&pool_g[tid], s);
    }
}

// ---------------------------------------------------------------------------
// head: grid 128 x 64.  pooled/N -> relu(@wo1+bo1) -> @wo2+bo2
// ---------------------------------------------------------------------------
__global__ __launch_bounds__(64)
void head_kernel(const float* __restrict__ wo1,     // [D,64]
                 const float* __restrict__ bo1,     // [64]
                 const float* __restrict__ wo2,     // [64,2]
                 const float* __restrict__ bo2,     // [2]
                 const float* __restrict__ ws,
                 float* __restrict__ out) {         // [B,2]
    const int b = blockIdx.x;
    const int t = threadIdx.x;
    __shared__ float z_l[64];

    const float* pooled = ws + POOL_OFF + b * D;
    float acc = bo1[t];
    #pragma unroll 4
    for (int e = 0; e < D; ++e)
        acc = fmaf(pooled[e] * (1.0f / (float)NN), wo1[e * 64 + t], acc);
    z_l[t] = fmaxf(acc, 0.f);
    __syncthreads();

    if (t < 2) {
        float o = bo2[t];
        #pragma unroll 4
        for (int k = 0; k < 64; ++k) o = fmaf(z_l[k], wo2[k * 2 + t], o);
        out[b * 2 + t] = o;
    }
}

extern "C" void kernel_launch(void* const* d_in, const int* in_sizes, int n_in,
                              void* d_out, int out_size, void* d_ws, size_t ws_size,
                              hipStream_t stream) {
    const float* cad    = (const float*)d_in[0];
    const float* w_dist = (const float*)d_in[1];
    const float* b_dist = (const float*)d_in[2];
    const float* w1     = (const float*)d_in[3];
    const float* b1     = (const float*)d_in[4];
    const float* w2     = (const float*)d_in[5];
    const float* b2     = (const float*)d_in[6];
    const float* wo1    = (const float*)d_in[7];
    const float* bo1    = (const float*)d_in[8];
    const float* wo2    = (const float*)d_in[9];
    const float* bo2    = (const float*)d_in[10];
    float* ws  = (float*)d_ws;
    float* out = (float*)d_out;

    prep_kernel<<<dim3(NN + 2 + BB), dim3(256), 0, stream>>>(cad, w_dist, b_dist, w1, b1, ws);
    gemm2_kernel<<<dim3(4, BB), dim3(256), 0, stream>>>(w2, b2, ws);
    head_kernel<<<dim3(BB), dim3(64), 0, stream>>>(wo1, bo1, wo2, bo2, ws, out);
}